// Round 7
// baseline (238.593 us; speedup 1.0000x reference)
//
#include <hip/hip_runtime.h>
#include <hip/hip_bf16.h>

// Problem constants
#define BB 512   // batch
#define SS 96    // seq len
#define NN 64    // nodes
#define HH 512   // hidden
#define EE 512   // edges per graph

typedef __attribute__((ext_vector_type(8))) short short8;   // 8 bf16 (4 VGPRs)
typedef __attribute__((ext_vector_type(4))) float f32x4;    // MFMA acc
typedef unsigned short u16;

__device__ __forceinline__ u16 f2bf(float f) {
    union { float f; unsigned u; } v; v.f = f;
    return (u16)((v.u + 0x7FFFu + ((v.u >> 16) & 1u)) >> 16);   // RNE
}
__device__ __forceinline__ short8 ld8bf(const u16* p) { return *(const short8*)p; }
__device__ __forceinline__ short8 cvt8(const float* p) {       // 8 fp32 -> bf16 frag
    float4 a = *(const float4*)p, b = *(const float4*)(p + 4);
    short8 r;
    r[0] = (short)f2bf(a.x); r[1] = (short)f2bf(a.y);
    r[2] = (short)f2bf(a.z); r[3] = (short)f2bf(a.w);
    r[4] = (short)f2bf(b.x); r[5] = (short)f2bf(b.y);
    r[6] = (short)f2bf(b.z); r[7] = (short)f2bf(b.w);
    return r;
}
__device__ __forceinline__ ushort4 packbf(f32x4 a) {
    ushort4 u; u.x = f2bf(a[0]); u.y = f2bf(a[1]); u.z = f2bf(a[2]); u.w = f2bf(a[3]);
    return u;
}

// ---------------------------------------------------------------------------
// k_prep: weights -> bf16; conv weight reordered (n,kw) -> (kw,n).
// ---------------------------------------------------------------------------
__global__ __launch_bounds__(256) void k_prep(const float* __restrict__ W1,
                                              const float* __restrict__ W2,
                                              const float* __restrict__ cw,
                                              u16* __restrict__ W1b,
                                              u16* __restrict__ W2b,
                                              u16* __restrict__ Wcb) {
    const int i0 = blockIdx.x * 256 + threadIdx.x, stp = gridDim.x * 256;
    for (int i = i0; i < HH * SS; i += stp) W1b[i] = f2bf(W1[i]);
    for (int i = i0; i < SS * HH; i += stp) W2b[i] = f2bf(W2[i]);
    for (int i = i0; i < HH * 192; i += stp) {
        int h = i / 192, q = i % 192, n = q / 3, kw = q % 3;
        Wcb[h * 192 + kw * 64 + n] = f2bf(cw[i]);
    }
}

// ---------------------------------------------------------------------------
// k_adj: one block per graph.  Builds normalized adjacency in bf16 [64][64]
// into workspace (4.2 MB total, L3-resident).  Hoisted out of k_all so the
// main kernel's barrier chain starts directly at MFMA0.
// ---------------------------------------------------------------------------
__global__ __launch_bounds__(256) void k_adj(const int* __restrict__ ei,
                                             u16* __restrict__ AsG) {
    const int b = blockIdx.x, t = threadIdx.x;
    __shared__ float Asm[4096];
    __shared__ int   deg[64];
    __shared__ float dinv[64];

    for (int i = t; i < 4096; i += 256) Asm[i] = 0.f;
    if (t < 64) deg[t] = 1;                          // self loop
    __syncthreads();
    const int* eb = ei + (size_t)b * 2 * EE;
    const int es0 = eb[t],       ed0 = eb[EE + t];
    const int es1 = eb[256 + t], ed1 = eb[EE + 256 + t];
    atomicAdd(&deg[ed0], 1);
    atomicAdd(&deg[ed1], 1);
    __syncthreads();
    if (t < 64) dinv[t] = rsqrtf((float)deg[t]);
    __syncthreads();
    atomicAdd(&Asm[ed0 * 64 + es0], dinv[es0] * dinv[ed0]);
    atomicAdd(&Asm[ed1 * 64 + es1], dinv[es1] * dinv[ed1]);
    if (t < 64) atomicAdd(&Asm[t * 64 + t], dinv[t] * dinv[t]);
    __syncthreads();
    u16* ab = AsG + (size_t)b * 4096;
    for (int i = t; i < 1024; i += 256) {
        int n = i >> 4, m4 = (i & 15) * 4;
        f32x4 v = *(const f32x4*)(Asm + n * 64 + m4);
        *(ushort4*)(ab + n * 64 + m4) = packbf(v);
    }
}

// ---------------------------------------------------------------------------
// k_all: one block of 256 threads (4 waves) per graph; round-0 per-wave
// workload (504 MFMA/wave, best ILP amortization) with the barrier chain cut:
//  - adjacency precomputed (k_adj); As fragments live in REGISTERS (MFMA0's
//    B-op and MFMA3's A-op need the SAME rows node=w*16+l16 -> load once)
//  - gb hoisted out of the hidden loop (rows loop-invariant)
//  - 4 barriers total (was ~10); LDS 27936 B -> 4 independent blocks/CU
//    (vs 2), naturally phase-skewed -> decorrelated stalls (round-6 lesson:
//    lockstep waves don't fill each other's stalls).
// LDS map (27936 B): Gs@0 [64][104] (13312) | H1c@13824 [64][72] (9216)
//   overlays: Ts@0 [96][72] (13824, over dead Gs after B2);
//             Hp@13824 [98][72] (14112, over dead H1c after B2).
// launch_bounds(256,4): VGPR cap 128 (round-6 lesson: never force below
// natural footprint ~100).
// ---------------------------------------------------------------------------
__global__ __launch_bounds__(256, 4) void k_all(const float* __restrict__ x,
                                                const u16* __restrict__ AsG,
                                                const u16* __restrict__ W1b,
                                                const float* __restrict__ b1,
                                                const u16* __restrict__ W2b,
                                                const float* __restrict__ b2,
                                                const u16* __restrict__ Wcb,
                                                float* __restrict__ out) {
    const int b = blockIdx.x, t = threadIdx.x;
    const int w = t >> 6, lane = t & 63, quad = lane >> 4, l16 = lane & 15;

    __shared__ __align__(16) char smem[27936];
    u16* Gs  = (u16*)smem;             // [64][104]
    u16* H1c = (u16*)(smem + 13824);   // [64][72]
    u16* Ts  = (u16*)smem;             // overlay: [96][72]
    u16* Hp  = (u16*)(smem + 13824);   // overlay: [98][72]

    // ---- As fragments: rows node=w*16+l16, shared by MFMA0(B-op) & MFMA3(A-op)
    const u16* asb = AsG + (size_t)b * 4096;
    short8 af[2];
    #pragma unroll
    for (int kc = 0; kc < 2; ++kc)
        af[kc] = ld8bf(asb + (w * 16 + l16) * 64 + kc * 32 + quad * 8);

    // ---- MFMA0: Gs[node][s] = X @ A^T ----
    const float* xb = x + (size_t)b * SS * NN;
    #pragma unroll
    for (int j = 0; j < 6; ++j) {
        f32x4 acc = (f32x4){0.f, 0.f, 0.f, 0.f};
        #pragma unroll
        for (int kc = 0; kc < 2; ++kc) {
            short8 a = cvt8(xb + (j * 16 + l16) * 64 + kc * 32 + quad * 8);
            acc = __builtin_amdgcn_mfma_f32_16x16x32_bf16(a, af[kc], acc, 0, 0, 0);
        }
        // col=l16 -> node=w*16+l16 ; row=quad*4+r -> s=j*16+quad*4+r
        *(ushort4*)(Gs + (w * 16 + l16) * 104 + j * 16 + quad * 4) = packbf(acc);
    }
    __syncthreads();                                   // B1

    // ---- gb hoist (rows wave-private, loop-invariant) ----
    short8 gb[3];
    #pragma unroll
    for (int kc = 0; kc < 3; ++kc)
        gb[kc] = ld8bf(Gs + (w * 16 + l16) * 104 + kc * 32 + quad * 8);

    // ---- hidden-chunk loop: hc 0..7, barrier-free (H1c rows wave-private) ----
    f32x4 accT[6];
    #pragma unroll
    for (int j = 0; j < 6; ++j) accT[j] = (f32x4){0.f, 0.f, 0.f, 0.f};

    for (int hc = 0; hc < 8; ++hc) {
        // MFMA1: C[h][node] -> H1c[node][h]
        #pragma unroll
        for (int hs = 0; hs < 4; ++hs) {
            f32x4 a1 = (f32x4){0.f, 0.f, 0.f, 0.f};
            #pragma unroll
            for (int kc = 0; kc < 3; ++kc) {
                short8 wa = ld8bf(W1b + (size_t)(hc * 64 + hs * 16 + l16) * 96 + kc * 32 + quad * 8);
                a1 = __builtin_amdgcn_mfma_f32_16x16x32_bf16(wa, gb[kc], a1, 0, 0, 0);
            }
            float4 bias = *(const float4*)(b1 + hc * 64 + hs * 16 + quad * 4);
            f32x4 r;
            r[0] = fmaxf(a1[0] + bias.x, 0.f); r[1] = fmaxf(a1[1] + bias.y, 0.f);
            r[2] = fmaxf(a1[2] + bias.z, 0.f); r[3] = fmaxf(a1[3] + bias.w, 0.f);
            *(ushort4*)(H1c + (w * 16 + l16) * 72 + hs * 16 + quad * 4) = packbf(r);
        }
        // MFMA2: accT[node][s] += H1c @ W2c^T
        short8 ha[2];
        #pragma unroll
        for (int kc = 0; kc < 2; ++kc)
            ha[kc] = ld8bf(H1c + (w * 16 + l16) * 72 + kc * 32 + quad * 8);
        #pragma unroll
        for (int j = 0; j < 6; ++j)
            #pragma unroll
            for (int kc = 0; kc < 2; ++kc) {
                short8 wb = ld8bf(W2b + (size_t)(j * 16 + l16) * HH + hc * 64 + kc * 32 + quad * 8);
                accT[j] = __builtin_amdgcn_mfma_f32_16x16x32_bf16(ha[kc], wb, accT[j], 0, 0, 0);
            }
    }

    __syncthreads();                                   // B2: Gs/H1c reads done
    // ---- Ts[s][m] <- accT (overlay on Gs) ----
    #pragma unroll
    for (int j = 0; j < 6; ++j)   // col=l16 -> s=j*16+l16 ; rows node=w*16+quad*4+r
        *(ushort4*)(Ts + (j * 16 + l16) * 72 + w * 16 + quad * 4) = packbf(accT[j]);
    __syncthreads();                                   // B3

    // ---- MFMA3: Hp[s+1][n] = A @ T + b2 (A frags in regs; pad folded) ----
    #pragma unroll
    for (int j = 0; j < 6; ++j) {
        f32x4 a3 = (f32x4){0.f, 0.f, 0.f, 0.f};
        #pragma unroll
        for (int kc = 0; kc < 2; ++kc) {
            short8 tb = ld8bf(Ts + (j * 16 + l16) * 72 + kc * 32 + quad * 8);
            a3 = __builtin_amdgcn_mfma_f32_16x16x32_bf16(af[kc], tb, a3, 0, 0, 0);
        }
        float bs = b2[j * 16 + l16];
        f32x4 r = {a3[0] + bs, a3[1] + bs, a3[2] + bs, a3[3] + bs};
        ushort4 pr = packbf(r);
        // col=l16 -> s=j*16+l16 ; rows n=w*16+quad*4+rr  (Hp over dead H1c)
        *(ushort4*)(Hp + (j * 16 + l16 + 1) * 72 + w * 16 + quad * 4) = pr;
        if (j == 5 && l16 == 15) *(ushort4*)(Hp + 0 * 72  + w * 16 + quad * 4) = pr;
        if (j == 0 && l16 == 0)  *(ushort4*)(Hp + 97 * 72 + w * 16 + quad * 4) = pr;
    }
    __syncthreads();                                   // B4

    // ---- conv: wave w = h-sub, 8 ht-tiles each (288 MFMA/wave) ----
    float* ob = out + (size_t)b * SS * HH;
    for (int ht = 0; ht < 8; ++ht) {
        short8 wa[6];
        #pragma unroll
        for (int kc = 0; kc < 6; ++kc)
            wa[kc] = ld8bf(Wcb + (size_t)(ht * 64 + w * 16 + l16) * 192 + kc * 32 + quad * 8);
        #pragma unroll
        for (int j = 0; j < 6; ++j) {
            f32x4 acc = (f32x4){0.f, 0.f, 0.f, 0.f};
            #pragma unroll
            for (int kc = 0; kc < 6; ++kc) {
                int kw = kc >> 1, nb = (kc & 1) * 32;
                short8 hb = ld8bf(Hp + (j * 16 + l16 + kw) * 72 + nb + quad * 8);
                acc = __builtin_amdgcn_mfma_f32_16x16x32_bf16(wa[kc], hb, acc, 0, 0, 0);
            }
            // col=l16 -> s=j*16+l16 ; rows h=ht*64+w*16+quad*4+rr
            float4 vv = {acc[0], acc[1], acc[2], acc[3]};
            *(float4*)(ob + (size_t)(j * 16 + l16) * HH + ht * 64 + w * 16 + quad * 4) = vv;
        }
    }
}

// ---------------------------------------------------------------------------
extern "C" void kernel_launch(void* const* d_in, const int* in_sizes, int n_in,
                              void* d_out, int out_size, void* d_ws, size_t ws_size,
                              hipStream_t stream) {
    const float* x  = (const float*)d_in[0];
    const int*   ei = (const int*)d_in[1];
    const float* W1 = (const float*)d_in[2];
    const float* b1 = (const float*)d_in[3];
    const float* W2 = (const float*)d_in[4];
    const float* b2 = (const float*)d_in[5];
    const float* cw = (const float*)d_in[6];
    float* out = (float*)d_out;

    char* wsp = (char*)d_ws;
    u16* W1b = (u16*)wsp;                    // 98,304 B
    u16* W2b = (u16*)(wsp + 98304);          // 98,304 B
    u16* Wcb = (u16*)(wsp + 196608);         // 196,608 B
    u16* AsG = (u16*)(wsp + 393216);         // 512*4096*2 = 4,194,304 B

    k_prep<<<96, 256, 0, stream>>>(W1, W2, cw, W1b, W2b, Wcb);
    k_adj <<<BB, 256, 0, stream>>>(ei, AsG);
    k_all <<<BB, 256, 0, stream>>>(x, AsG, W1b, b1, W2b, b2, Wcb, out);
}

// Round 8
// 201.486 us; speedup vs baseline: 1.1842x; 1.1842x over previous
//
#include <hip/hip_runtime.h>
#include <hip/hip_bf16.h>

// Problem constants
#define BB 512   // batch
#define SS 96    // seq len
#define NN 64    // nodes
#define HH 512   // hidden
#define EE 512   // edges per graph

typedef __attribute__((ext_vector_type(8))) short short8;   // 8 bf16 (4 VGPRs)
typedef __attribute__((ext_vector_type(4))) float f32x4;    // MFMA acc
typedef unsigned short u16;

__device__ __forceinline__ u16 f2bf(float f) {
    union { float f; unsigned u; } v; v.f = f;
    return (u16)((v.u + 0x7FFFu + ((v.u >> 16) & 1u)) >> 16);   // RNE
}
__device__ __forceinline__ short8 ld8bf(const u16* p) { return *(const short8*)p; }
__device__ __forceinline__ short8 cvt8r(float4 a, float4 b) {  // 8 fp32 regs -> bf16 frag
    short8 r;
    r[0] = (short)f2bf(a.x); r[1] = (short)f2bf(a.y);
    r[2] = (short)f2bf(a.z); r[3] = (short)f2bf(a.w);
    r[4] = (short)f2bf(b.x); r[5] = (short)f2bf(b.y);
    r[6] = (short)f2bf(b.z); r[7] = (short)f2bf(b.w);
    return r;
}
__device__ __forceinline__ ushort4 packbf(f32x4 a) {
    ushort4 u; u.x = f2bf(a[0]); u.y = f2bf(a[1]); u.z = f2bf(a[2]); u.w = f2bf(a[3]);
    return u;
}

// ---------------------------------------------------------------------------
// k_prep: weights -> bf16; conv weight reordered (n,kw) -> (kw,n).
// ---------------------------------------------------------------------------
__global__ __launch_bounds__(256) void k_prep(const float* __restrict__ W1,
                                              const float* __restrict__ W2,
                                              const float* __restrict__ cw,
                                              u16* __restrict__ W1b,
                                              u16* __restrict__ W2b,
                                              u16* __restrict__ Wcb) {
    const int i0 = blockIdx.x * 256 + threadIdx.x, stp = gridDim.x * 256;
    for (int i = i0; i < HH * SS; i += stp) W1b[i] = f2bf(W1[i]);
    for (int i = i0; i < SS * HH; i += stp) W2b[i] = f2bf(W2[i]);
    for (int i = i0; i < HH * 192; i += stp) {
        int h = i / 192, q = i % 192, n = q / 3, kw = q % 3;
        Wcb[h * 192 + kw * 64 + n] = f2bf(cw[i]);
    }
}

// ---------------------------------------------------------------------------
// k_all: round-4 baseline (70.6us) + ROUND-8 BISECTION PROBE: the hidden-
// chunk loop is run TWICE.  The first (dummy) pass uses opaque-copied
// pointers/operands (asm, defeats CSE) and a discarded accumulator (asm
// keep-alive).  Dummy H1 writes are overwritten by the real pass before any
// cross-wave use (rows wave-private, LDS ops program-ordered within a wave),
// so output is bit-identical.  dur(r8)-dur(r4) = marginal cost of one
// hidden-loop pass -> isolates which phase owns the unexplained ~58us/CU.
// ---------------------------------------------------------------------------
__global__ __launch_bounds__(512, 4) void k_all(const float* __restrict__ x,
                                                const int* __restrict__ ei,
                                                const u16* __restrict__ W1b,
                                                const float* __restrict__ b1,
                                                const u16* __restrict__ W2b,
                                                const float* __restrict__ b2,
                                                const u16* __restrict__ Wcb,
                                                float* __restrict__ out) {
    const int b = blockIdx.x, t = threadIdx.x;
    const int w = t >> 6, lane = t & 63, quad = lane >> 4, l16 = lane & 15;
    const int wg = w & 3, wh = w >> 2;

    __shared__ __align__(16) char smem[57344];
    u16*   As   = (u16*)smem;                 // [64][72]
    u16*   Gs   = (u16*)(smem + 9216);        // [64][104]
    u16*   H1   = (u16*)(smem + 22528);       // [2][64][72]
    u16*   Ts   = (u16*)(smem + 9216);        // overlay: [2][96][72]
    float* Asm  = (float*)(smem + 40960);     // [64][64]
    u16*   Hp   = (u16*)(smem + 40960);       // overlay: [98][72]
    int*   deg  = (int*)(smem + 9216);
    float* dinv = (float*)(smem + 9472);

    // ---- x prefetch ----
    const float* xb = x + (size_t)b * SS * NN;
    float4 xp[3][2][2];
    #pragma unroll
    for (int jj = 0; jj < 3; ++jj)
        #pragma unroll
        for (int kc = 0; kc < 2; ++kc) {
            const float* p = xb + ((wh * 3 + jj) * 16 + l16) * 64 + kc * 32 + quad * 8;
            xp[jj][kc][0] = *(const float4*)p;
            xp[jj][kc][1] = *(const float4*)(p + 4);
        }

    // ---- phase 0: normalized adjacency ----
    for (int i = t; i < 4096; i += 512) Asm[i] = 0.f;
    if (t < 64) deg[t] = 1;                         // self loop
    __syncthreads();
    const int* eb = ei + (size_t)b * 2 * EE;
    const int es = eb[t], ed = eb[EE + t];          // E == 512 == blockDim
    atomicAdd(&deg[ed], 1);
    __syncthreads();
    if (t < 64) dinv[t] = rsqrtf((float)deg[t]);
    __syncthreads();
    atomicAdd(&Asm[ed * 64 + es], dinv[es] * dinv[ed]);
    if (t < 64) atomicAdd(&Asm[t * 64 + t], dinv[t] * dinv[t]);
    __syncthreads();
    // As bf16 [64][72]
    for (int i = t; i < 1024; i += 512) {
        int n = i >> 4, m4 = (i & 15) * 4;
        f32x4 v = *(const f32x4*)(Asm + n * 64 + m4);
        *(ushort4*)(As + n * 72 + m4) = packbf(v);
    }
    __syncthreads();

    // ---- MFMA0: Gs[node][s] = X @ A^T ----
    {
        short8 bf0[2];
        #pragma unroll
        for (int kc = 0; kc < 2; ++kc)
            bf0[kc] = ld8bf(As + (wg * 16 + l16) * 72 + kc * 32 + quad * 8);
        #pragma unroll
        for (int jj = 0; jj < 3; ++jj) {
            const int j = wh * 3 + jj;
            f32x4 acc = (f32x4){0.f, 0.f, 0.f, 0.f};
            #pragma unroll
            for (int kc = 0; kc < 2; ++kc) {
                short8 a = cvt8r(xp[jj][kc][0], xp[jj][kc][1]);
                acc = __builtin_amdgcn_mfma_f32_16x16x32_bf16(a, bf0[kc], acc, 0, 0, 0);
            }
            *(ushort4*)(Gs + (wg * 16 + l16) * 104 + j * 16 + quad * 4) = packbf(acc);
        }
    }
    __syncthreads();

    // ---- gb fragments (loop-invariant) ----
    short8 gb[3];
    #pragma unroll
    for (int kc = 0; kc < 3; ++kc)
        gb[kc] = ld8bf(Gs + (wg * 16 + l16) * 104 + kc * 32 + quad * 8);

    u16* H1w = H1 + wh * (64 * 72);

    // ==== ROUND-8 BISECTION PROBE: dummy hidden-loop pass ====
    {
        size_t off1 = 0, off2 = 0;
        asm volatile("" : "+s"(off1), "+s"(off2));       // opaque zero offsets
        const u16* W1d = W1b + off1;
        const u16* W2d = W2b + off2;
        short8 gbd[3];
        #pragma unroll
        for (int kc = 0; kc < 3; ++kc) {
            gbd[kc] = gb[kc];
            asm volatile("" : "+v"(gbd[kc]));            // opaque copy: no CSE
        }
        f32x4 accD[6];
        #pragma unroll
        for (int j = 0; j < 6; ++j) accD[j] = (f32x4){0.f, 0.f, 0.f, 0.f};
        #pragma unroll
        for (int hcc = 0; hcc < 4; ++hcc) {
            const int hc = wh * 4 + hcc;
            short8 w2d[6][2];
            #pragma unroll
            for (int j = 0; j < 6; ++j)
                #pragma unroll
                for (int kc = 0; kc < 2; ++kc)
                    w2d[j][kc] = ld8bf(W2d + (size_t)(j * 16 + l16) * HH + hc * 64 + kc * 32 + quad * 8);
            #pragma unroll
            for (int hs = 0; hs < 4; ++hs) {
                f32x4 a1 = (f32x4){0.f, 0.f, 0.f, 0.f};
                #pragma unroll
                for (int kc = 0; kc < 3; ++kc) {
                    short8 wa = ld8bf(W1d + (size_t)(hc * 64 + hs * 16 + l16) * 96 + kc * 32 + quad * 8);
                    a1 = __builtin_amdgcn_mfma_f32_16x16x32_bf16(wa, gbd[kc], a1, 0, 0, 0);
                }
                float4 bias = *(const float4*)(b1 + hc * 64 + hs * 16 + quad * 4);
                f32x4 r;
                r[0] = fmaxf(a1[0] + bias.x, 0.f); r[1] = fmaxf(a1[1] + bias.y, 0.f);
                r[2] = fmaxf(a1[2] + bias.z, 0.f); r[3] = fmaxf(a1[3] + bias.w, 0.f);
                *(ushort4*)(H1w + (wg * 16 + l16) * 72 + hs * 16 + quad * 4) = packbf(r);
            }
            short8 ha[2];
            #pragma unroll
            for (int kc = 0; kc < 2; ++kc)
                ha[kc] = ld8bf(H1w + (wg * 16 + l16) * 72 + kc * 32 + quad * 8);
            #pragma unroll
            for (int j = 0; j < 6; ++j)
                #pragma unroll
                for (int kc = 0; kc < 2; ++kc)
                    accD[j] = __builtin_amdgcn_mfma_f32_16x16x32_bf16(ha[kc], w2d[j][kc], accD[j], 0, 0, 0);
        }
        #pragma unroll
        for (int j = 0; j < 6; ++j)
            asm volatile("" :: "v"(accD[j]));            // keep-alive, then dead
    }
    // ==== end probe ====

    // ---- REAL hidden-chunk loop (identical to round 4) ----
    f32x4 accT[6];
    #pragma unroll
    for (int j = 0; j < 6; ++j) accT[j] = (f32x4){0.f, 0.f, 0.f, 0.f};

    #pragma unroll
    for (int hcc = 0; hcc < 4; ++hcc) {
        const int hc = wh * 4 + hcc;
        short8 w2r[6][2];
        #pragma unroll
        for (int j = 0; j < 6; ++j)
            #pragma unroll
            for (int kc = 0; kc < 2; ++kc)
                w2r[j][kc] = ld8bf(W2b + (size_t)(j * 16 + l16) * HH + hc * 64 + kc * 32 + quad * 8);
        #pragma unroll
        for (int hs = 0; hs < 4; ++hs) {
            f32x4 a1 = (f32x4){0.f, 0.f, 0.f, 0.f};
            #pragma unroll
            for (int kc = 0; kc < 3; ++kc) {
                short8 wa = ld8bf(W1b + (size_t)(hc * 64 + hs * 16 + l16) * 96 + kc * 32 + quad * 8);
                a1 = __builtin_amdgcn_mfma_f32_16x16x32_bf16(wa, gb[kc], a1, 0, 0, 0);
            }
            float4 bias = *(const float4*)(b1 + hc * 64 + hs * 16 + quad * 4);
            f32x4 r;
            r[0] = fmaxf(a1[0] + bias.x, 0.f); r[1] = fmaxf(a1[1] + bias.y, 0.f);
            r[2] = fmaxf(a1[2] + bias.z, 0.f); r[3] = fmaxf(a1[3] + bias.w, 0.f);
            *(ushort4*)(H1w + (wg * 16 + l16) * 72 + hs * 16 + quad * 4) = packbf(r);
        }
        short8 ha[2];
        #pragma unroll
        for (int kc = 0; kc < 2; ++kc)
            ha[kc] = ld8bf(H1w + (wg * 16 + l16) * 72 + kc * 32 + quad * 8);
        #pragma unroll
        for (int j = 0; j < 6; ++j)
            #pragma unroll
            for (int kc = 0; kc < 2; ++kc)
                accT[j] = __builtin_amdgcn_mfma_f32_16x16x32_bf16(ha[kc], w2r[j][kc], accT[j], 0, 0, 0);
    }

    // ---- Ts[wh][s][m] <- accT ----
    __syncthreads();
    u16* Tsw = Ts + wh * (96 * 72);
    #pragma unroll
    for (int j = 0; j < 6; ++j)
        *(ushort4*)(Tsw + (j * 16 + l16) * 72 + wg * 16 + quad * 4) = packbf(accT[j]);
    __syncthreads();

    // ---- MFMA3: Hp[s+1][n] = A @ (Ts0 + Ts1) + b2 ; pad rows folded in ----
    {
        short8 af[2];
        #pragma unroll
        for (int kc = 0; kc < 2; ++kc)
            af[kc] = ld8bf(As + (wg * 16 + l16) * 72 + kc * 32 + quad * 8);
        #pragma unroll
        for (int jj = 0; jj < 3; ++jj) {
            const int j = wh * 3 + jj;
            f32x4 a3 = (f32x4){0.f, 0.f, 0.f, 0.f};
            #pragma unroll
            for (int h = 0; h < 2; ++h)
                #pragma unroll
                for (int kc = 0; kc < 2; ++kc) {
                    short8 tb = ld8bf(Ts + h * (96 * 72) + (j * 16 + l16) * 72 + kc * 32 + quad * 8);
                    a3 = __builtin_amdgcn_mfma_f32_16x16x32_bf16(af[kc], tb, a3, 0, 0, 0);
                }
            float bs = b2[j * 16 + l16];
            f32x4 r = {a3[0] + bs, a3[1] + bs, a3[2] + bs, a3[3] + bs};
            ushort4 pr = packbf(r);
            *(ushort4*)(Hp + (j * 16 + l16 + 1) * 72 + wg * 16 + quad * 4) = pr;
            if (j == 5 && l16 == 15) *(ushort4*)(Hp + 0 * 72  + wg * 16 + quad * 4) = pr;
            if (j == 0 && l16 == 0)  *(ushort4*)(Hp + 97 * 72 + wg * 16 + quad * 4) = pr;
        }
    }
    __syncthreads();

    // ---- conv: 8-wave split ----
    const int wc = w & 3, wt = w >> 2;
    float* ob = out + (size_t)b * SS * HH;
    #pragma unroll
    for (int htt = 0; htt < 4; ++htt) {
        const int ht = wt * 4 + htt;
        short8 wa[6];
        #pragma unroll
        for (int kc = 0; kc < 6; ++kc)
            wa[kc] = ld8bf(Wcb + (size_t)(ht * 64 + wc * 16 + l16) * 192 + kc * 32 + quad * 8);
        #pragma unroll
        for (int j = 0; j < 6; ++j) {
            f32x4 acc = (f32x4){0.f, 0.f, 0.f, 0.f};
            #pragma unroll
            for (int kc = 0; kc < 6; ++kc) {
                int kw = kc >> 1, nb = (kc & 1) * 32;
                short8 hb = ld8bf(Hp + (j * 16 + l16 + kw) * 72 + nb + quad * 8);
                acc = __builtin_amdgcn_mfma_f32_16x16x32_bf16(wa[kc], hb, acc, 0, 0, 0);
            }
            float4 vv = {acc[0], acc[1], acc[2], acc[3]};
            *(float4*)(ob + (size_t)(j * 16 + l16) * HH + ht * 64 + wc * 16 + quad * 4) = vv;
        }
    }
}

// ---------------------------------------------------------------------------
extern "C" void kernel_launch(void* const* d_in, const int* in_sizes, int n_in,
                              void* d_out, int out_size, void* d_ws, size_t ws_size,
                              hipStream_t stream) {
    const float* x  = (const float*)d_in[0];
    const int*   ei = (const int*)d_in[1];
    const float* W1 = (const float*)d_in[2];
    const float* b1 = (const float*)d_in[3];
    const float* W2 = (const float*)d_in[4];
    const float* b2 = (const float*)d_in[5];
    const float* cw = (const float*)d_in[6];
    float* out = (float*)d_out;

    char* wsp = (char*)d_ws;                 // 384 KiB of workspace used
    u16* W1b = (u16*)wsp;                    // 98,304 B
    u16* W2b = (u16*)(wsp + 98304);          // 98,304 B
    u16* Wcb = (u16*)(wsp + 196608);         // 196,608 B

    k_prep<<<96, 256, 0, stream>>>(W1, W2, cw, W1b, W2b, Wcb);
    k_all <<<BB, 512, 0, stream>>>(x, ei, W1b, b1, W2b, b2, Wcb, out);
}

// Round 9
// 151.044 us; speedup vs baseline: 1.5796x; 1.3340x over previous
//
#include <hip/hip_runtime.h>
#include <hip/hip_bf16.h>

// Problem constants
#define BB 512   // batch
#define SS 96    // seq len
#define NN 64    // nodes
#define HH 512   // hidden
#define EE 512   // edges per graph

typedef __attribute__((ext_vector_type(8))) short short8;   // 8 bf16 (4 VGPRs)
typedef __attribute__((ext_vector_type(4))) float f32x4;    // MFMA acc
typedef unsigned short u16;

__device__ __forceinline__ u16 f2bf(float f) {
    union { float f; unsigned u; } v; v.f = f;
    return (u16)((v.u + 0x7FFFu + ((v.u >> 16) & 1u)) >> 16);   // RNE
}
__device__ __forceinline__ short8 ld8bf(const u16* p) { return *(const short8*)p; }
__device__ __forceinline__ short8 cvt8(const float* p) {       // 8 fp32 -> bf16 frag
    float4 a = *(const float4*)p, b = *(const float4*)(p + 4);
    short8 r;
    r[0] = (short)f2bf(a.x); r[1] = (short)f2bf(a.y);
    r[2] = (short)f2bf(a.z); r[3] = (short)f2bf(a.w);
    r[4] = (short)f2bf(b.x); r[5] = (short)f2bf(b.y);
    r[6] = (short)f2bf(b.z); r[7] = (short)f2bf(b.w);
    return r;
}
__device__ __forceinline__ ushort4 packbf(f32x4 a) {
    ushort4 u; u.x = f2bf(a[0]); u.y = f2bf(a[1]); u.z = f2bf(a[2]); u.w = f2bf(a[3]);
    return u;
}

// Staged-chunk geometry: per hc (64 hidden), one contiguous 27136-B pair:
//   [0,13312):  W1 chunk  [64 rows h][104 u16] (cols 96..103 pad)
//   [13312,27136): W2 chunk [96 rows s][72 u16] (cols 64..71 pad)
// Strides 104/72 u16 give <=2-way within-quad LDS bank aliasing on b128 reads.
#define CHUNK_B  27136
#define CHUNK_U  13568
#define W2OFF_U  6656

// ---------------------------------------------------------------------------
// k_prep: conv weight reorder (unchanged) + W12s staged-chunk-pair layout.
// ---------------------------------------------------------------------------
__global__ __launch_bounds__(256) void k_prep(const float* __restrict__ W1,
                                              const float* __restrict__ W2,
                                              const float* __restrict__ cw,
                                              u16* __restrict__ Wcb,
                                              u16* __restrict__ W12s) {
    const int i0 = blockIdx.x * 256 + threadIdx.x, stp = gridDim.x * 256;
    for (int i = i0; i < HH * 192; i += stp) {
        int h = i / 192, q = i % 192, n = q / 3, kw = q % 3;
        Wcb[h * 192 + kw * 64 + n] = f2bf(cw[i]);
    }
    for (int i = i0; i < 8 * CHUNK_U; i += stp) {
        int hc = i / CHUNK_U, q = i % CHUNK_U;
        float v = 0.f;
        if (q < W2OFF_U) {                         // W1 part [64][104]
            int r = q / 104, c = q % 104;
            if (c < 96) v = W1[(hc * 64 + r) * 96 + c];
        } else {                                   // W2 part [96][72]
            int q2 = q - W2OFF_U, s = q2 / 72, c = q2 % 72;
            if (c < 64) v = W2[s * 512 + hc * 64 + c];
        }
        W12s[i] = f2bf(v);
    }
}

// ---------------------------------------------------------------------------
// k_all: FUSED, 512 threads (8 waves) per graph.  ROUND-9: LDS weight staging.
// r8 bisection: hidden loop = 34us of 71, bound by redundant per-wave L2
// weight streaming (786 MB/pass device-wide).  Now each chunk is staged to
// LDS ONCE per block (196KB floor), double-buffered via reg-relay (T14:
// loads issued at iter top hide under MFMA1; ds_write into idle buffer).
// New 8-wave split: wg=w&3 node-group, p=w>>2 (hs-pair / j-half); ALL waves
// march the same hc 0..7 -> Ts tree-reduce eliminated, accT 24->12 regs.
// Biases staged to LDS (b1 per-hs dependent global loads were hidden serial
// latency at VGPR=64).  Blocks stay lockstep (r7 lesson: keeps weights L2-hot).
// LDS map (79744 B):
//   buf0@0(27136) buf1@27136(27136) Gs@54272[64][104](13312)
//   H1@67584[64][72](9216) b1L@76800(2048) b2L@78848(384)
//   deg@79232(256) dinv@79488(256)
//   overlays: As[64][72]@27136 (in buf1; dead after af-regs, pre-loop)
//             Asm f32[4096]@54272 (phase0; dead before MFMA0 writes Gs)
//             Ts[96][72]@0 (over buf0, post-loop) Hp[98][72]@13824
//   2 blocks/CU (159488 <= 163840); launch_bounds(512,4) caps VGPR 128.
// ---------------------------------------------------------------------------
__global__ __launch_bounds__(512, 4) void k_all(const float* __restrict__ x,
                                                const int* __restrict__ ei,
                                                const float* __restrict__ b1,
                                                const float* __restrict__ b2,
                                                const u16* __restrict__ Wcb,
                                                const u16* __restrict__ W12s,
                                                float* __restrict__ out) {
    const int b = blockIdx.x, t = threadIdx.x;
    const int w = t >> 6, lane = t & 63, quad = lane >> 4, l16 = lane & 15;
    const int wg = w & 3, p = w >> 2;

    __shared__ __align__(16) char smem[79744];
    u16*   Gs   = (u16*)(smem + 54272);
    u16*   H1   = (u16*)(smem + 67584);
    float* b1L  = (float*)(smem + 76800);
    float* b2L  = (float*)(smem + 78848);
    u16*   As   = (u16*)(smem + 27136);
    float* Asm  = (float*)(smem + 54272);
    int*   deg  = (int*)(smem + 79232);
    float* dinv = (float*)(smem + 79488);
    u16*   Ts   = (u16*)smem;             // overlay (post-loop)
    u16*   Hp   = (u16*)(smem + 13824);   // overlay (post-loop)

    // ---- staging offsets (flat 16B units over one 27136-B chunk-pair) ----
    int so[4];
    #pragma unroll
    for (int rr = 0; rr < 4; ++rr) so[rr] = rr * 8192 + w * 1024 + lane * 16;

    // ---- issue hc0 stage loads + bias copies (latency hides under phase0) ----
    const char* wsrc = (const char*)W12s;
    short8 st[4];
    #pragma unroll
    for (int rr = 0; rr < 4; ++rr)
        if (so[rr] < CHUNK_B) st[rr] = ld8bf((const u16*)(wsrc + so[rr]));
    b1L[t] = b1[t];
    if (t < 96) b2L[t] = b2[t];

    // ---- phase 0: normalized adjacency ----
    for (int i = t; i < 4096; i += 512) Asm[i] = 0.f;
    if (t < 64) deg[t] = 1;                         // self loop
    __syncthreads();
    const int* eb = ei + (size_t)b * 2 * EE;
    const int es = eb[t], ed = eb[EE + t];          // E == 512 == blockDim
    atomicAdd(&deg[ed], 1);
    __syncthreads();
    if (t < 64) dinv[t] = rsqrtf((float)deg[t]);
    __syncthreads();
    atomicAdd(&Asm[ed * 64 + es], dinv[es] * dinv[ed]);
    if (t < 64) atomicAdd(&Asm[t * 64 + t], dinv[t] * dinv[t]);
    __syncthreads();
    for (int i = t; i < 1024; i += 512) {           // As bf16 [64][72]
        int n = i >> 4, m4 = (i & 15) * 4;
        f32x4 v = *(const f32x4*)(Asm + n * 64 + m4);
        *(ushort4*)(As + n * 72 + m4) = packbf(v);
    }
    __syncthreads();

    // ---- As fragments -> regs (MFMA0 B-op and MFMA3 A-op use same rows) ----
    short8 af[2];
    #pragma unroll
    for (int kc = 0; kc < 2; ++kc)
        af[kc] = ld8bf(As + (wg * 16 + l16) * 72 + kc * 32 + quad * 8);

    // ---- ds_write staged hc0 -> buf0 (disjoint from As) ----
    #pragma unroll
    for (int rr = 0; rr < 4; ++rr)
        if (so[rr] < CHUNK_B) *(short8*)(smem + so[rr]) = st[rr];

    // ---- MFMA0: Gs[node][s] = X @ A^T  (wave: nodes=wg, j-half=p) ----
    {
        const float* xb = x + (size_t)b * SS * NN;
        #pragma unroll
        for (int jj = 0; jj < 3; ++jj) {
            const int j = p * 3 + jj;
            f32x4 acc = (f32x4){0.f, 0.f, 0.f, 0.f};
            #pragma unroll
            for (int kc = 0; kc < 2; ++kc) {
                short8 a = cvt8(xb + (j * 16 + l16) * 64 + kc * 32 + quad * 8);
                acc = __builtin_amdgcn_mfma_f32_16x16x32_bf16(a, af[kc], acc, 0, 0, 0);
            }
            // col=l16 -> node=wg*16+l16 ; row=quad*4+r -> s=j*16+quad*4+r
            *(ushort4*)(Gs + (wg * 16 + l16) * 104 + j * 16 + quad * 4) = packbf(acc);
        }
    }
    __syncthreads();                           // B1: Gs + buf0 visible

    short8 gb[3];
    #pragma unroll
    for (int kc = 0; kc < 3; ++kc)
        gb[kc] = ld8bf(Gs + (wg * 16 + l16) * 104 + kc * 32 + quad * 8);

    // ---- hidden loop: all waves on same hc; wave (wg,p) does hs={2p,2p+1},
    //      j = p*3..p*3+2.  Double-buffered chunk staging via reg-relay. ----
    f32x4 accT[3];
    #pragma unroll
    for (int jj = 0; jj < 3; ++jj) accT[jj] = (f32x4){0.f, 0.f, 0.f, 0.f};

    for (int hc = 0; hc < 8; ++hc) {
        const u16* wbuf = (const u16*)(smem + (hc & 1) * CHUNK_B);
        // issue next chunk's loads (land during MFMA1 + barrier)
        if (hc < 7) {
            const char* src = wsrc + (size_t)(hc + 1) * CHUNK_B;
            #pragma unroll
            for (int rr = 0; rr < 4; ++rr)
                if (so[rr] < CHUNK_B) st[rr] = ld8bf((const u16*)(src + so[rr]));
        }
        // MFMA1: C[h][node] -> H1[node][h]   (hs = 2p+hh)
        #pragma unroll
        for (int hh = 0; hh < 2; ++hh) {
            const int hs = 2 * p + hh;
            f32x4 a1 = (f32x4){0.f, 0.f, 0.f, 0.f};
            #pragma unroll
            for (int kc = 0; kc < 3; ++kc) {
                short8 wa = ld8bf(wbuf + (hs * 16 + l16) * 104 + kc * 32 + quad * 8);
                a1 = __builtin_amdgcn_mfma_f32_16x16x32_bf16(wa, gb[kc], a1, 0, 0, 0);
            }
            float4 bias = *(const float4*)(b1L + hc * 64 + hs * 16 + quad * 4);
            f32x4 r;
            r[0] = fmaxf(a1[0] + bias.x, 0.f); r[1] = fmaxf(a1[1] + bias.y, 0.f);
            r[2] = fmaxf(a1[2] + bias.z, 0.f); r[3] = fmaxf(a1[3] + bias.w, 0.f);
            *(ushort4*)(H1 + (wg * 16 + l16) * 72 + hs * 16 + quad * 4) = packbf(r);
        }
        __syncthreads();                       // B_a: H1 complete
        // relay staged regs into the idle buffer (readers of it finished at
        // previous iteration's end barrier)
        if (hc < 7) {
            char* dst = smem + ((hc + 1) & 1) * CHUNK_B;
            #pragma unroll
            for (int rr = 0; rr < 4; ++rr)
                if (so[rr] < CHUNK_B) *(short8*)(dst + so[rr]) = st[rr];
        }
        // MFMA2: accT[node][s] += H1 @ W2c^T  (j = p*3+jj)
        short8 ha[2];
        #pragma unroll
        for (int kc = 0; kc < 2; ++kc)
            ha[kc] = ld8bf(H1 + (wg * 16 + l16) * 72 + kc * 32 + quad * 8);
        #pragma unroll
        for (int jj = 0; jj < 3; ++jj) {
            const int j = p * 3 + jj;
            #pragma unroll
            for (int kc = 0; kc < 2; ++kc) {
                short8 wb = ld8bf(wbuf + W2OFF_U + (j * 16 + l16) * 72 + kc * 32 + quad * 8);
                accT[jj] = __builtin_amdgcn_mfma_f32_16x16x32_bf16(ha[kc], wb, accT[jj], 0, 0, 0);
            }
        }
        __syncthreads();                       // B_b: buf reads done + stage visible
    }

    // ---- Ts[s][m] <- accT  (single buffer, no tree: j-ownership disjoint) ----
    #pragma unroll
    for (int jj = 0; jj < 3; ++jj) {
        const int j = p * 3 + jj;   // col=l16 -> s=j*16+l16 ; rows node=wg*16+quad*4+r
        *(ushort4*)(Ts + (j * 16 + l16) * 72 + wg * 16 + quad * 4) = packbf(accT[jj]);
    }
    __syncthreads();

    // ---- MFMA3: Hp[s+1][n] = A @ T + b2 (af in regs; pad folded in) ----
    #pragma unroll
    for (int jj = 0; jj < 3; ++jj) {
        const int j = p * 3 + jj;
        f32x4 a3 = (f32x4){0.f, 0.f, 0.f, 0.f};
        #pragma unroll
        for (int kc = 0; kc < 2; ++kc) {
            short8 tb = ld8bf(Ts + (j * 16 + l16) * 72 + kc * 32 + quad * 8);
            a3 = __builtin_amdgcn_mfma_f32_16x16x32_bf16(af[kc], tb, a3, 0, 0, 0);
        }
        float bs = b2L[j * 16 + l16];
        f32x4 r = {a3[0] + bs, a3[1] + bs, a3[2] + bs, a3[3] + bs};
        ushort4 pr = packbf(r);
        // col=l16 -> s=j*16+l16 ; rows n=wg*16+quad*4+rr
        *(ushort4*)(Hp + (j * 16 + l16 + 1) * 72 + wg * 16 + quad * 4) = pr;
        if (j == 5 && l16 == 15) *(ushort4*)(Hp + 0 * 72  + wg * 16 + quad * 4) = pr;
        if (j == 0 && l16 == 0)  *(ushort4*)(Hp + 97 * 72 + wg * 16 + quad * 4) = pr;
    }
    __syncthreads();

    // ---- conv: 8-wave split (wc = h-sub within ht, wt picks 4 ht-tiles) ----
    const int wc = w & 3, wt = w >> 2;
    float* ob = out + (size_t)b * SS * HH;
    #pragma unroll
    for (int htt = 0; htt < 4; ++htt) {
        const int ht = wt * 4 + htt;
        short8 wa[6];
        #pragma unroll
        for (int kc = 0; kc < 6; ++kc)
            wa[kc] = ld8bf(Wcb + (size_t)(ht * 64 + wc * 16 + l16) * 192 + kc * 32 + quad * 8);
        #pragma unroll
        for (int j = 0; j < 6; ++j) {
            f32x4 acc = (f32x4){0.f, 0.f, 0.f, 0.f};
            #pragma unroll
            for (int kc = 0; kc < 6; ++kc) {
                int kw = kc >> 1, nb = (kc & 1) * 32;
                short8 hb = ld8bf(Hp + (j * 16 + l16 + kw) * 72 + nb + quad * 8);
                acc = __builtin_amdgcn_mfma_f32_16x16x32_bf16(wa[kc], hb, acc, 0, 0, 0);
            }
            // col=l16 -> s=j*16+l16 ; rows h=ht*64+wc*16+quad*4+rr
            float4 vv = {acc[0], acc[1], acc[2], acc[3]};
            *(float4*)(ob + (size_t)(j * 16 + l16) * HH + ht * 64 + wc * 16 + quad * 4) = vv;
        }
    }
}

// ---------------------------------------------------------------------------
extern "C" void kernel_launch(void* const* d_in, const int* in_sizes, int n_in,
                              void* d_out, int out_size, void* d_ws, size_t ws_size,
                              hipStream_t stream) {
    const float* x  = (const float*)d_in[0];
    const int*   ei = (const int*)d_in[1];
    const float* W1 = (const float*)d_in[2];
    const float* b1 = (const float*)d_in[3];
    const float* W2 = (const float*)d_in[4];
    const float* b2 = (const float*)d_in[5];
    const float* cw = (const float*)d_in[6];
    float* out = (float*)d_out;

    char* wsp = (char*)d_ws;
    u16* Wcb  = (u16*)wsp;                   // 196,608 B
    u16* W12s = (u16*)(wsp + 196608);        // 217,088 B (8 chunk-pairs)

    k_prep<<<96, 256, 0, stream>>>(W1, W2, cw, Wcb, W12s);
    k_all <<<BB, 512, 0, stream>>>(x, ei, b1, b2, Wcb, W12s, out);
}